// Round 1
// baseline (160.702 us; speedup 1.0000x reference)
//
#include <hip/hip_runtime.h>
#include <math.h>

#define N_NODES 50000
#define F_IN 32
#define DEG 32
#define BATCH 2048

// ---------------- Kernel A: h0 = relu(feat @ w_mlp + b_mlp) ----------------
// 4 nodes per 256-thread block; w_mlp (32x64) staged in LDS.
__global__ void mlp_kernel(const float* __restrict__ feat,
                           const float* __restrict__ w,
                           const float* __restrict__ b,
                           float* __restrict__ h0) {
    __shared__ float wl[F_IN * 64];
    __shared__ float fl[4 * F_IN];
    int tid = threadIdx.x;
    for (int i = tid; i < F_IN * 64; i += 256) wl[i] = w[i];
    int n0 = blockIdx.x * 4;
    if (tid < 4 * F_IN) fl[tid] = feat[(size_t)n0 * F_IN + tid];
    __syncthreads();
    int local = tid >> 6;   // 0..3
    int j = tid & 63;       // 0..63
    float acc = b[j];
#pragma unroll
    for (int k = 0; k < F_IN; ++k) acc += fl[local * F_IN + k] * wl[k * 64 + j];
    h0[(size_t)(n0 + local) * 64 + j] = fmaxf(acc, 0.f);
}

__device__ __forceinline__ void softmax3(float a0, float a1, float a2,
                                         float& w0, float& w1, float& w2) {
    float m = fmaxf(a0, fmaxf(a1, a2));
    float e0 = __expf(a0 - m), e1 = __expf(a1 - m), e2 = __expf(a2 - m);
    float s = 1.f / (e0 + e1 + e2);
    w0 = e0 * s; w1 = e1 * s; w2 = e2 * s;
}

// ---------------- Kernel B: layer-1 InterAgg for all N nodes ----------------
// One node per 64-thread block; lane j = feature j of the 64-dim embedding.
// Writes inter1 (N x 128).
__global__ void layer1_kernel(const int* __restrict__ adj,
                              const float* __restrict__ h0,
                              const float* __restrict__ alpha1,
                              float* __restrict__ inter1) {
    int n = blockIdx.x;
    int j = threadIdx.x;  // 0..63
    __shared__ int nb[96];
    for (int q = j; q < 96; q += 64) {
        int r = q >> 5, d = q & 31;
        nb[q] = adj[(size_t)r * N_NODES * DEG + (size_t)n * DEG + d];
    }
    __syncthreads();
    float acc0 = 0.f, acc1 = 0.f, acc2 = 0.f;
#pragma unroll 8
    for (int d = 0; d < 32; ++d) acc0 += h0[(size_t)nb[d] * 64 + j];
#pragma unroll 8
    for (int d = 0; d < 32; ++d) acc1 += h0[(size_t)nb[32 + d] * 64 + j];
#pragma unroll 8
    for (int d = 0; d < 32; ++d) acc2 += h0[(size_t)nb[64 + d] * 64 + j];
    const float inv = 1.f / 32.f;
    acc0 *= inv; acc1 *= inv; acc2 *= inv;
    float selfv = h0[(size_t)n * 64 + j];
    // softmax(alpha1, axis=1): rows e=j and e=64+j, alpha1 is (128,3) row-major
    float w0, w1, w2, v0, v1, v2;
    softmax3(alpha1[j * 3 + 0], alpha1[j * 3 + 1], alpha1[j * 3 + 2], w0, w1, w2);
    softmax3(alpha1[(64 + j) * 3 + 0], alpha1[(64 + j) * 3 + 1], alpha1[(64 + j) * 3 + 2],
             v0, v1, v2);
    inter1[(size_t)n * 128 + j] = w0 * acc0 + w1 * acc1 + w2 * acc2;
    inter1[(size_t)n * 128 + 64 + j] =
        v0 * (selfv - acc0) + v1 * (selfv - acc1) + v2 * (selfv - acc2);
}

// ------- Kernel C: layer-2 InterAgg (batch only) + fused dense head -------
// One batch node per 128-thread block; lane j = feature j of the 128-dim emb.
__global__ void layer2_kernel(const int* __restrict__ nodes,
                              const int* __restrict__ adj,
                              const float* __restrict__ h0,
                              const float* __restrict__ inter1,
                              const float* __restrict__ alpha2,
                              const float* __restrict__ w_d2,
                              const float* __restrict__ b_d2,
                              const float* __restrict__ w_d1,
                              const float* __restrict__ b_d1,
                              const float* __restrict__ prior,
                              float* __restrict__ out) {
    int bb = blockIdx.x;
    int tid = threadIdx.x;  // 0..127
    int n = nodes[bb];
    __shared__ int nb[96];
    if (tid < 96) {
        int r = tid >> 5, d = tid & 31;
        nb[tid] = adj[(size_t)r * N_NODES * DEG + (size_t)n * DEG + d];
    }
    __syncthreads();
    int j = tid;
    float acc0 = 0.f, acc1 = 0.f, acc2 = 0.f;
#pragma unroll 8
    for (int d = 0; d < 32; ++d) acc0 += inter1[(size_t)nb[d] * 128 + j];
#pragma unroll 8
    for (int d = 0; d < 32; ++d) acc1 += inter1[(size_t)nb[32 + d] * 128 + j];
#pragma unroll 8
    for (int d = 0; d < 32; ++d) acc2 += inter1[(size_t)nb[64 + d] * 128 + j];
    const float inv = 1.f / 32.f;
    acc0 *= inv; acc1 *= inv; acc2 *= inv;
    float selfe = inter1[(size_t)n * 128 + j];
    float w0, w1, w2, v0, v1, v2;
    softmax3(alpha2[j * 3 + 0], alpha2[j * 3 + 1], alpha2[j * 3 + 2], w0, w1, w2);
    softmax3(alpha2[(128 + j) * 3 + 0], alpha2[(128 + j) * 3 + 1],
             alpha2[(128 + j) * 3 + 2], v0, v1, v2);
    // h2 = [self_full(192) | inter2(256)]; thread j owns h2[192+j] and h2[320+j]
    float i2a = w0 * acc0 + w1 * acc1 + w2 * acc2;
    float i2b = v0 * (selfe - acc0) + v1 * (selfe - acc1) + v2 * (selfe - acc2);
    float p0 = i2a * w_d2[(192 + j) * 2 + 0] + i2b * w_d2[(320 + j) * 2 + 0];
    float p1 = i2a * w_d2[(192 + j) * 2 + 1] + i2b * w_d2[(320 + j) * 2 + 1];
    // self_full[i]: i<64 -> h0[n][i]; 64<=i<192 -> inter1[n][i-64]
    float sf = (j < 64) ? h0[(size_t)n * 64 + j] : inter1[(size_t)n * 128 + (j - 64)];
    p0 += sf * w_d2[j * 2 + 0];
    p1 += sf * w_d2[j * 2 + 1];
    if (j < 64) {
        float sf2 = inter1[(size_t)n * 128 + 64 + j];  // self_full[128+j]
        p0 += sf2 * w_d2[(128 + j) * 2 + 0];
        p1 += sf2 * w_d2[(128 + j) * 2 + 1];
    }
    // block reduction: wave64 shuffle, then cross-wave via LDS
#pragma unroll
    for (int off = 32; off > 0; off >>= 1) {
        p0 += __shfl_down(p0, off, 64);
        p1 += __shfl_down(p1, off, 64);
    }
    __shared__ float s0[2], s1[2];
    int wave = tid >> 6, lane = tid & 63;
    if (lane == 0) { s0[wave] = p0; s1[wave] = p1; }
    __syncthreads();
    if (tid == 0) {
        float x0 = s0[0] + s0[1] + b_d2[0];
        float x1 = s1[0] + s1[1] + b_d2[1];
        x0 = x0 > 0.f ? x0 : 0.3f * x0;  // leaky_relu slope 0.3
        x1 = x1 > 0.f ? x1 : 0.3f * x1;
        x0 += __logf(prior[0]);
        x1 += __logf(prior[1]);
        float z = x0 * w_d1[0] + x1 * w_d1[1] + b_d1[0];
        out[bb] = 1.f / (1.f + __expf(-z));
    }
}

extern "C" void kernel_launch(void* const* d_in, const int* in_sizes, int n_in,
                              void* d_out, int out_size, void* d_ws, size_t ws_size,
                              hipStream_t stream) {
    const int*   nodes  = (const int*)d_in[0];
    const float* feat   = (const float*)d_in[1];
    const int*   adj    = (const int*)d_in[2];
    const float* prior  = (const float*)d_in[3];
    const float* w_mlp  = (const float*)d_in[4];
    const float* b_mlp  = (const float*)d_in[5];
    const float* alpha1 = (const float*)d_in[6];
    const float* alpha2 = (const float*)d_in[7];
    const float* w_d2   = (const float*)d_in[8];
    const float* b_d2   = (const float*)d_in[9];
    const float* w_d1   = (const float*)d_in[10];
    const float* b_d1   = (const float*)d_in[11];
    float* out = (float*)d_out;

    // workspace: h0 (N x 64) then inter1 (N x 128) — 38.4 MB total
    float* h0     = (float*)d_ws;
    float* inter1 = h0 + (size_t)N_NODES * 64;

    mlp_kernel<<<N_NODES / 4, 256, 0, stream>>>(feat, w_mlp, b_mlp, h0);
    layer1_kernel<<<N_NODES, 64, 0, stream>>>(adj, h0, alpha1, inter1);
    layer2_kernel<<<BATCH, 128, 0, stream>>>(nodes, adj, h0, inter1, alpha2,
                                             w_d2, b_d2, w_d1, b_d1, prior, out);
}

// Round 2
// 83.952 us; speedup vs baseline: 1.9142x; 1.9142x over previous
//
#include <hip/hip_runtime.h>
#include <hip/hip_fp16.h>
#include <math.h>

#define N_NODES 50000
#define F_IN 32
#define DEG 32
#define BATCH 2048

typedef _Float16 half8 __attribute__((ext_vector_type(8)));
typedef _Float16 half4v __attribute__((ext_vector_type(4)));

__device__ __forceinline__ void softmax3(float a0, float a1, float a2,
                                         float& w0, float& w1, float& w2) {
    float m = fmaxf(a0, fmaxf(a1, a2));
    float e0 = __expf(a0 - m), e1 = __expf(a1 - m), e2 = __expf(a2 - m);
    float s = 1.f / (e0 + e1 + e2);
    w0 = e0 * s; w1 = e1 * s; w2 = e2 * s;
}

// ---- Kernel A: h0 = relu(feat @ w_mlp + b) -> fp16; block 0 also builds
// softmax(alpha1), softmax(alpha2) tables in ws. 4 nodes / 256-thread block.
__global__ void mlp_kernel(const float* __restrict__ feat,
                           const float* __restrict__ w,
                           const float* __restrict__ b,
                           const float* __restrict__ alpha1,
                           const float* __restrict__ alpha2,
                           float* __restrict__ sw1,    // 128*3
                           float* __restrict__ sw2,    // 256*3
                           _Float16* __restrict__ h0) {
    __shared__ float wl[F_IN * 64];
    __shared__ float fl[4 * F_IN];
    int tid = threadIdx.x;
    if (blockIdx.x == 0) {
        for (int q = tid; q < 384; q += 256) {
            const float* src = (q < 128) ? (alpha1 + q * 3) : (alpha2 + (q - 128) * 3);
            float* dst = (q < 128) ? (sw1 + q * 3) : (sw2 + (q - 128) * 3);
            float w0, w1, w2;
            softmax3(src[0], src[1], src[2], w0, w1, w2);
            dst[0] = w0; dst[1] = w1; dst[2] = w2;
        }
    }
    for (int i = tid; i < F_IN * 64; i += 256) wl[i] = w[i];
    int n0 = blockIdx.x * 4;
    if (tid < 4 * F_IN) fl[tid] = feat[(size_t)n0 * F_IN + tid];
    __syncthreads();
    int local = tid >> 6;
    int j = tid & 63;
    float acc = b[j];
#pragma unroll
    for (int k = 0; k < F_IN; ++k) acc += fl[local * F_IN + k] * wl[k * 64 + j];
    h0[(size_t)(n0 + local) * 64 + j] = (_Float16)fmaxf(acc, 0.f);
}

// ---- Kernel B: layer-1 InterAgg for all N nodes, fp16 in/out.
// 4 nodes/block, one wave per node. Lane j: g=j>>3 (row group), e=j&7
// (feature octet). Each gather instr reads 8 rows x 128B via half8.
__global__ __launch_bounds__(256) void layer1_kernel(
        const int* __restrict__ adj,
        const _Float16* __restrict__ h0,
        const float* __restrict__ sw1,
        _Float16* __restrict__ out) {
    __shared__ int nb[4][96];
    int tid = threadIdx.x;
    int n0 = blockIdx.x * 4;
    for (int q = tid; q < 384; q += 256) {
        int local = q / 96, idx = q - local * 96;
        int r = idx >> 5, d = idx & 31;
        nb[local][idx] = adj[((size_t)r * N_NODES + (n0 + local)) * DEG + d];
    }
    __syncthreads();
    int local = tid >> 6, j = tid & 63;
    int n = n0 + local;
    int g = j >> 3, e = j & 7;
    int idxs[12];
#pragma unroll
    for (int t = 0; t < 12; ++t) idxs[t] = nb[local][t * 8 + g];
    float acc[3][8];
#pragma unroll
    for (int r = 0; r < 3; ++r)
#pragma unroll
        for (int i = 0; i < 8; ++i) acc[r][i] = 0.f;
#pragma unroll
    for (int t = 0; t < 12; ++t) {
        half8 v = *reinterpret_cast<const half8*>(h0 + (size_t)idxs[t] * 64 + 8 * e);
#pragma unroll
        for (int i = 0; i < 8; ++i) acc[t >> 2][i] += (float)v[i];
    }
    // combine across the 8 row-groups: strides 8,16,32
#pragma unroll
    for (int m = 8; m <= 32; m <<= 1)
#pragma unroll
        for (int r = 0; r < 3; ++r)
#pragma unroll
            for (int i = 0; i < 8; ++i) acc[r][i] += __shfl_xor(acc[r][i], m, 64);

    half8 sv = *reinterpret_cast<const half8*>(h0 + (size_t)n * 64 + 8 * e);
    // softmax weights for features f=8e+i (agg rows) and 64+f (diff rows)
    float wA[24], wB[24];
    {
        const float4* pa = reinterpret_cast<const float4*>(sw1 + 24 * e);
        const float4* pb = reinterpret_cast<const float4*>(sw1 + 192 + 24 * e);
#pragma unroll
        for (int q = 0; q < 6; ++q) {
            float4 ta = pa[q], tb = pb[q];
            wA[4 * q] = ta.x; wA[4 * q + 1] = ta.y; wA[4 * q + 2] = ta.z; wA[4 * q + 3] = ta.w;
            wB[4 * q] = tb.x; wB[4 * q + 1] = tb.y; wB[4 * q + 2] = tb.z; wB[4 * q + 3] = tb.w;
        }
    }
    const float inv = 1.f / 32.f;
    half8 ha, hb;
#pragma unroll
    for (int i = 0; i < 8; ++i) {
        float a0 = acc[0][i] * inv, a1 = acc[1][i] * inv, a2 = acc[2][i] * inv;
        float s = (float)sv[i];
        float oa = wA[i * 3] * a0 + wA[i * 3 + 1] * a1 + wA[i * 3 + 2] * a2;
        float ob = wB[i * 3] * (s - a0) + wB[i * 3 + 1] * (s - a1) + wB[i * 3 + 2] * (s - a2);
        ha[i] = (_Float16)oa;
        hb[i] = (_Float16)ob;
    }
    if (g == 0)
        *reinterpret_cast<half8*>(out + (size_t)n * 128 + 8 * e) = ha;
    else if (g == 1)
        *reinterpret_cast<half8*>(out + (size_t)n * 128 + 64 + 8 * e) = hb;
}

// ---- Kernel C: layer-2 InterAgg (batch) + fused dense head.
// 4 batch nodes/block, one wave per node. Lane j: g=j>>4 (row group, 4 rows
// per instr), e=j&15 (feature octet of the 128-dim emb).
__global__ __launch_bounds__(256) void layer2_kernel(
        const int* __restrict__ nodes,
        const int* __restrict__ adj,
        const _Float16* __restrict__ h0,
        const _Float16* __restrict__ i1,
        const float* __restrict__ sw2,
        const float* __restrict__ w_d2,
        const float* __restrict__ b_d2,
        const float* __restrict__ w_d1,
        const float* __restrict__ b_d1,
        const float* __restrict__ prior,
        float* __restrict__ out) {
    __shared__ int nb[4][96];
    __shared__ int nid[4];
    int tid = threadIdx.x;
    int b0 = blockIdx.x * 4;
    if (tid < 4) nid[tid] = nodes[b0 + tid];
    __syncthreads();
    for (int q = tid; q < 384; q += 256) {
        int local = q / 96, idx = q - local * 96;
        int r = idx >> 5, d = idx & 31;
        nb[local][idx] = adj[((size_t)r * N_NODES + nid[local]) * DEG + d];
    }
    __syncthreads();
    int local = tid >> 6, j = tid & 63;
    int bb = b0 + local;
    int n = nid[local];
    int g = j >> 4, e = j & 15;
    int idxs[24];
#pragma unroll
    for (int t = 0; t < 24; ++t) idxs[t] = nb[local][t * 4 + g];
    float acc[3][8];
#pragma unroll
    for (int r = 0; r < 3; ++r)
#pragma unroll
        for (int i = 0; i < 8; ++i) acc[r][i] = 0.f;
#pragma unroll
    for (int t = 0; t < 24; ++t) {
        half8 v = *reinterpret_cast<const half8*>(i1 + (size_t)idxs[t] * 128 + 8 * e);
#pragma unroll
        for (int i = 0; i < 8; ++i) acc[t >> 3][i] += (float)v[i];
    }
#pragma unroll
    for (int m = 16; m <= 32; m <<= 1)
#pragma unroll
        for (int r = 0; r < 3; ++r)
#pragma unroll
            for (int i = 0; i < 8; ++i) acc[r][i] += __shfl_xor(acc[r][i], m, 64);

    const float inv = 1.f / 32.f;
    float p0 = 0.f, p1 = 0.f;
    if (g == 0) {
        // inter2 contribution for features f=8e..8e+7
        half8 sv = *reinterpret_cast<const half8*>(i1 + (size_t)n * 128 + 8 * e);
        float wA[24], wB[24];
        const float4* pa = reinterpret_cast<const float4*>(sw2 + 24 * e);
        const float4* pb = reinterpret_cast<const float4*>(sw2 + 384 + 24 * e);
#pragma unroll
        for (int q = 0; q < 6; ++q) {
            float4 ta = pa[q], tb = pb[q];
            wA[4 * q] = ta.x; wA[4 * q + 1] = ta.y; wA[4 * q + 2] = ta.z; wA[4 * q + 3] = ta.w;
            wB[4 * q] = tb.x; wB[4 * q + 1] = tb.y; wB[4 * q + 2] = tb.z; wB[4 * q + 3] = tb.w;
        }
#pragma unroll
        for (int i = 0; i < 8; ++i) {
            int f = 8 * e + i;
            float a0 = acc[0][i] * inv, a1 = acc[1][i] * inv, a2 = acc[2][i] * inv;
            float s = (float)sv[i];
            float i2a = wA[i * 3] * a0 + wA[i * 3 + 1] * a1 + wA[i * 3 + 2] * a2;
            float i2b = wB[i * 3] * (s - a0) + wB[i * 3 + 1] * (s - a1) + wB[i * 3 + 2] * (s - a2);
            p0 += i2a * w_d2[(192 + f) * 2 + 0] + i2b * w_d2[(320 + f) * 2 + 0];
            p1 += i2a * w_d2[(192 + f) * 2 + 1] + i2b * w_d2[(320 + f) * 2 + 1];
        }
    } else if (g == 1) {
        // self h0 features 4e..4e+3
        half4v sv = *reinterpret_cast<const half4v*>(h0 + (size_t)n * 64 + 4 * e);
#pragma unroll
        for (int i = 0; i < 4; ++i) {
            int f = 4 * e + i;
            float s = (float)sv[i];
            p0 += s * w_d2[f * 2 + 0];
            p1 += s * w_d2[f * 2 + 1];
        }
    } else if (g == 2) {
        // self inter1 features 8e..8e+7 -> w_d2 rows 64+f
        half8 sv = *reinterpret_cast<const half8*>(i1 + (size_t)n * 128 + 8 * e);
#pragma unroll
        for (int i = 0; i < 8; ++i) {
            int f = 8 * e + i;
            float s = (float)sv[i];
            p0 += s * w_d2[(64 + f) * 2 + 0];
            p1 += s * w_d2[(64 + f) * 2 + 1];
        }
    }
#pragma unroll
    for (int m = 1; m <= 32; m <<= 1) {
        p0 += __shfl_xor(p0, m, 64);
        p1 += __shfl_xor(p1, m, 64);
    }
    if (j == 0) {
        float x0 = p0 + b_d2[0], x1 = p1 + b_d2[1];
        x0 = x0 > 0.f ? x0 : 0.3f * x0;
        x1 = x1 > 0.f ? x1 : 0.3f * x1;
        x0 += __logf(prior[0]);
        x1 += __logf(prior[1]);
        float z = x0 * w_d1[0] + x1 * w_d1[1] + b_d1[0];
        out[bb] = 1.f / (1.f + __expf(-z));
    }
}

extern "C" void kernel_launch(void* const* d_in, const int* in_sizes, int n_in,
                              void* d_out, int out_size, void* d_ws, size_t ws_size,
                              hipStream_t stream) {
    const int*   nodes  = (const int*)d_in[0];
    const float* feat   = (const float*)d_in[1];
    const int*   adj    = (const int*)d_in[2];
    const float* prior  = (const float*)d_in[3];
    const float* w_mlp  = (const float*)d_in[4];
    const float* b_mlp  = (const float*)d_in[5];
    const float* alpha1 = (const float*)d_in[6];
    const float* alpha2 = (const float*)d_in[7];
    const float* w_d2   = (const float*)d_in[8];
    const float* b_d2   = (const float*)d_in[9];
    const float* w_d1   = (const float*)d_in[10];
    const float* b_d1   = (const float*)d_in[11];
    float* out = (float*)d_out;

    // ws layout: sw1 (128*3 f32) | sw2 (256*3 f32) | pad to 8192B |
    //            h0 fp16 (N*64)  | inter1 fp16 (N*128)   (~19.2 MB)
    float* sw1 = (float*)d_ws;
    float* sw2 = sw1 + 128 * 3;
    _Float16* h0f = (_Float16*)((char*)d_ws + 8192);
    _Float16* i1f = h0f + (size_t)N_NODES * 64;

    mlp_kernel<<<N_NODES / 4, 256, 0, stream>>>(feat, w_mlp, b_mlp, alpha1, alpha2,
                                                sw1, sw2, h0f);
    layer1_kernel<<<N_NODES / 4, 256, 0, stream>>>(adj, h0f, sw1, i1f);
    layer2_kernel<<<BATCH / 4, 256, 0, stream>>>(nodes, adj, h0f, i1f, sw2,
                                                 w_d2, b_d2, w_d1, b_d1, prior, out);
}

// Round 3
// 71.426 us; speedup vs baseline: 2.2499x; 1.1754x over previous
//
#include <hip/hip_runtime.h>
#include <hip/hip_fp16.h>
#include <math.h>

#define N_NODES 50000
#define F_IN 32
#define DEG 32
#define BATCH 2048

typedef _Float16 half8 __attribute__((ext_vector_type(8)));

__device__ __forceinline__ void softmax3(float a0, float a1, float a2,
                                         float& w0, float& w1, float& w2) {
    float m = fmaxf(a0, fmaxf(a1, a2));
    float e0 = __expf(a0 - m), e1 = __expf(a1 - m), e2 = __expf(a2 - m);
    float s = 1.f / (e0 + e1 + e2);
    w0 = e0 * s; w1 = e1 * s; w2 = e2 * s;
}

__device__ __forceinline__ half8 shfl_xor_h8(half8 x, int m) {
    int4 a = __builtin_bit_cast(int4, x);
    a.x = __shfl_xor(a.x, m, 64);
    a.y = __shfl_xor(a.y, m, 64);
    a.z = __shfl_xor(a.z, m, 64);
    a.w = __shfl_xor(a.w, m, 64);
    return __builtin_bit_cast(half8, a);
}

// ---- Kernel A: h0 = relu(feat @ w_mlp + b) -> fp16, grid-strided.
// Block 0 also builds softmax(alpha1/alpha2) tables in ws.
__global__ __launch_bounds__(256) void mlp_kernel(
        const float* __restrict__ feat,
        const float* __restrict__ w,
        const float* __restrict__ b,
        const float* __restrict__ alpha1,
        const float* __restrict__ alpha2,
        float* __restrict__ sw1,    // 128*3
        float* __restrict__ sw2,    // 256*3
        _Float16* __restrict__ h0) {
    __shared__ float wl[F_IN * 64];
    __shared__ float fl[2][4 * F_IN];
    int tid = threadIdx.x;
    if (blockIdx.x == 0) {
        for (int q = tid; q < 384; q += 256) {
            const float* src = (q < 128) ? (alpha1 + q * 3) : (alpha2 + (q - 128) * 3);
            float* dst = (q < 128) ? (sw1 + q * 3) : (sw2 + (q - 128) * 3);
            float w0, w1, w2;
            softmax3(src[0], src[1], src[2], w0, w1, w2);
            dst[0] = w0; dst[1] = w1; dst[2] = w2;
        }
    }
    for (int i = tid; i < F_IN * 64; i += 256) wl[i] = w[i];
    int local = tid >> 6;
    int j = tid & 63;
    float bj = b[j];
    int buf = 0;
    const int nquads = N_NODES / 4;  // 12500
    for (int q = blockIdx.x; q < nquads; q += gridDim.x) {
        if (tid < 4 * F_IN) fl[buf][tid] = feat[(size_t)q * 4 * F_IN + tid];
        __syncthreads();
        float acc = bj;
#pragma unroll
        for (int k = 0; k < F_IN; ++k) acc += fl[buf][local * F_IN + k] * wl[k * 64 + j];
        h0[(size_t)(q * 4 + local) * 64 + j] = (_Float16)fmaxf(acc, 0.f);
        buf ^= 1;
    }
}

// ---- Kernel B: layer-1 InterAgg for all N nodes, fp16 in/out, packed math.
// 4 nodes/block, one wave per node. Lane j: g=j>>3 (row group), e=j&7
// (feature octet). Each gather instr reads 8 rows x 128B via half8.
__global__ __launch_bounds__(256) void layer1_kernel(
        const int* __restrict__ adj,
        const _Float16* __restrict__ h0,
        const float* __restrict__ sw1,
        _Float16* __restrict__ out) {
    __shared__ int nb[4][96];
    __shared__ float swl[384];  // wA(192) | wB(192)
    int tid = threadIdx.x;
    int n0 = blockIdx.x * 4;
    if (tid < 96)
        reinterpret_cast<float4*>(swl)[tid] = reinterpret_cast<const float4*>(sw1)[tid];
    for (int q = tid; q < 384; q += 256) {
        int local = q / 96, idx = q - local * 96;
        int r = idx >> 5, d = idx & 31;
        nb[local][idx] = adj[((size_t)r * N_NODES + (n0 + local)) * DEG + d];
    }
    __syncthreads();
    int local = tid >> 6, j = tid & 63;
    int n = n0 + local;
    int g = j >> 3, e = j & 7;
    int idxs[12];
#pragma unroll
    for (int t = 0; t < 12; ++t) idxs[t] = nb[local][t * 8 + g];
    half8 acc0 = {}, acc1 = {}, acc2 = {};
#pragma unroll
    for (int t = 0; t < 4; ++t)
        acc0 += *reinterpret_cast<const half8*>(h0 + (size_t)idxs[t] * 64 + 8 * e);
#pragma unroll
    for (int t = 4; t < 8; ++t)
        acc1 += *reinterpret_cast<const half8*>(h0 + (size_t)idxs[t] * 64 + 8 * e);
#pragma unroll
    for (int t = 8; t < 12; ++t)
        acc2 += *reinterpret_cast<const half8*>(h0 + (size_t)idxs[t] * 64 + 8 * e);
    // combine across the 8 row-groups (packed): strides 8,16,32
#pragma unroll
    for (int m = 8; m <= 32; m <<= 1) {
        acc0 += shfl_xor_h8(acc0, m);
        acc1 += shfl_xor_h8(acc1, m);
        acc2 += shfl_xor_h8(acc2, m);
    }
    if (g < 2) {
        // g==0: A[f] = sum_r wA[3f+r]*a_r ; g==1: B[f] = sum_r wB[3f+r]*(s-a_r)
        half8 sv = *reinterpret_cast<const half8*>(h0 + (size_t)n * 64 + 8 * e);
        const float* wt = swl + g * 192 + 24 * e;
        const float inv = 1.f / 32.f;
        float sgn = g ? -1.f : 1.f;
        half8 res;
#pragma unroll
        for (int i = 0; i < 8; ++i) {
            float base = g ? (float)sv[i] : 0.f;
            float t0 = fmaf(sgn, (float)acc0[i] * inv, base);
            float t1 = fmaf(sgn, (float)acc1[i] * inv, base);
            float t2 = fmaf(sgn, (float)acc2[i] * inv, base);
            res[i] = (_Float16)(wt[3 * i] * t0 + wt[3 * i + 1] * t1 + wt[3 * i + 2] * t2);
        }
        *reinterpret_cast<half8*>(out + (size_t)n * 128 + g * 64 + 8 * e) = res;
    }
}

// ---- Kernel C: layer-2 InterAgg (batch) + fused dense head, packed math.
// 4 batch nodes/block, one wave per node. g=j>>4 (4 rows/instr), e=j&15.
__global__ __launch_bounds__(256) void layer2_kernel(
        const int* __restrict__ nodes,
        const int* __restrict__ adj,
        const _Float16* __restrict__ h0,
        const _Float16* __restrict__ i1,
        const float* __restrict__ sw2,
        const float* __restrict__ w_d2,
        const float* __restrict__ b_d2,
        const float* __restrict__ w_d1,
        const float* __restrict__ b_d1,
        const float* __restrict__ prior,
        float* __restrict__ out) {
    __shared__ int nb[4][96];
    __shared__ int nid[4];
    __shared__ float swl[768];  // wA(384) | wB(384)
    int tid = threadIdx.x;
    int b0 = blockIdx.x * 4;
    if (tid < 4) nid[tid] = nodes[b0 + tid];
    if (tid >= 64 && tid < 256) {
        int q = tid - 64;  // 192 float4 = 768 floats
        reinterpret_cast<float4*>(swl)[q] = reinterpret_cast<const float4*>(sw2)[q];
    }
    __syncthreads();
    for (int q = tid; q < 384; q += 256) {
        int local = q / 96, idx = q - local * 96;
        int r = idx >> 5, d = idx & 31;
        nb[local][idx] = adj[((size_t)r * N_NODES + nid[local]) * DEG + d];
    }
    __syncthreads();
    int local = tid >> 6, j = tid & 63;
    int bb = b0 + local;
    int n = nid[local];
    int g = j >> 4, e = j & 15;
    int idxs[24];
#pragma unroll
    for (int t = 0; t < 24; ++t) idxs[t] = nb[local][t * 4 + g];
    half8 acc0 = {}, acc1 = {}, acc2 = {};
#pragma unroll
    for (int t = 0; t < 8; ++t)
        acc0 += *reinterpret_cast<const half8*>(i1 + (size_t)idxs[t] * 128 + 8 * e);
#pragma unroll
    for (int t = 8; t < 16; ++t)
        acc1 += *reinterpret_cast<const half8*>(i1 + (size_t)idxs[t] * 128 + 8 * e);
#pragma unroll
    for (int t = 16; t < 24; ++t)
        acc2 += *reinterpret_cast<const half8*>(i1 + (size_t)idxs[t] * 128 + 8 * e);
#pragma unroll
    for (int m = 16; m <= 32; m <<= 1) {
        acc0 += shfl_xor_h8(acc0, m);
        acc1 += shfl_xor_h8(acc1, m);
        acc2 += shfl_xor_h8(acc2, m);
    }
    const float inv = 1.f / 32.f;
    float p0 = 0.f, p1 = 0.f;
    if (g == 0) {
        // inter2 contribution for features f=8e..8e+7
        half8 sv = *reinterpret_cast<const half8*>(i1 + (size_t)n * 128 + 8 * e);
        const float* wa = swl + 24 * e;
        const float* wb = swl + 384 + 24 * e;
#pragma unroll
        for (int i = 0; i < 8; ++i) {
            int f = 8 * e + i;
            float a0 = (float)acc0[i] * inv, a1 = (float)acc1[i] * inv,
                  a2 = (float)acc2[i] * inv;
            float s = (float)sv[i];
            float i2a = wa[3 * i] * a0 + wa[3 * i + 1] * a1 + wa[3 * i + 2] * a2;
            float i2b = wb[3 * i] * (s - a0) + wb[3 * i + 1] * (s - a1) +
                        wb[3 * i + 2] * (s - a2);
            p0 += i2a * w_d2[(192 + f) * 2 + 0] + i2b * w_d2[(320 + f) * 2 + 0];
            p1 += i2a * w_d2[(192 + f) * 2 + 1] + i2b * w_d2[(320 + f) * 2 + 1];
        }
    } else if (g == 1) {
        // self h0 features 4e..4e+3
#pragma unroll
        for (int i = 0; i < 4; ++i) {
            int f = 4 * e + i;
            float s = (float)h0[(size_t)n * 64 + f];
            p0 += s * w_d2[f * 2 + 0];
            p1 += s * w_d2[f * 2 + 1];
        }
    } else if (g == 2) {
        // self inter1 features 8e..8e+7 -> w_d2 rows 64+f
        half8 sv = *reinterpret_cast<const half8*>(i1 + (size_t)n * 128 + 8 * e);
#pragma unroll
        for (int i = 0; i < 8; ++i) {
            int f = 8 * e + i;
            float s = (float)sv[i];
            p0 += s * w_d2[(64 + f) * 2 + 0];
            p1 += s * w_d2[(64 + f) * 2 + 1];
        }
    }
#pragma unroll
    for (int m = 1; m <= 32; m <<= 1) {
        p0 += __shfl_xor(p0, m, 64);
        p1 += __shfl_xor(p1, m, 64);
    }
    if (j == 0) {
        float x0 = p0 + b_d2[0], x1 = p1 + b_d2[1];
        x0 = x0 > 0.f ? x0 : 0.3f * x0;
        x1 = x1 > 0.f ? x1 : 0.3f * x1;
        x0 += __logf(prior[0]);
        x1 += __logf(prior[1]);
        float z = x0 * w_d1[0] + x1 * w_d1[1] + b_d1[0];
        out[bb] = 1.f / (1.f + __expf(-z));
    }
}

extern "C" void kernel_launch(void* const* d_in, const int* in_sizes, int n_in,
                              void* d_out, int out_size, void* d_ws, size_t ws_size,
                              hipStream_t stream) {
    const int*   nodes  = (const int*)d_in[0];
    const float* feat   = (const float*)d_in[1];
    const int*   adj    = (const int*)d_in[2];
    const float* prior  = (const float*)d_in[3];
    const float* w_mlp  = (const float*)d_in[4];
    const float* b_mlp  = (const float*)d_in[5];
    const float* alpha1 = (const float*)d_in[6];
    const float* alpha2 = (const float*)d_in[7];
    const float* w_d2   = (const float*)d_in[8];
    const float* b_d2   = (const float*)d_in[9];
    const float* w_d1   = (const float*)d_in[10];
    const float* b_d1   = (const float*)d_in[11];
    float* out = (float*)d_out;

    // ws layout: sw1 (128*3 f32) | sw2 (256*3 f32) | pad to 8192B |
    //            h0 fp16 (N*64)  | inter1 fp16 (N*128)
    float* sw1 = (float*)d_ws;
    float* sw2 = sw1 + 128 * 3;
    _Float16* h0f = (_Float16*)((char*)d_ws + 8192);
    _Float16* i1f = h0f + (size_t)N_NODES * 64;

    mlp_kernel<<<2048, 256, 0, stream>>>(feat, w_mlp, b_mlp, alpha1, alpha2,
                                         sw1, sw2, h0f);
    layer1_kernel<<<N_NODES / 4, 256, 0, stream>>>(adj, h0f, sw1, i1f);
    layer2_kernel<<<BATCH / 4, 256, 0, stream>>>(nodes, adj, h0f, i1f, sw2,
                                                 w_d2, b_d2, w_d1, b_d1, prior, out);
}